// Round 1
// baseline (239.271 us; speedup 1.0000x reference)
//
#include <hip/hip_runtime.h>
#include <math.h>

#define D_    64
#define K_    1024
#define N_    131072
#define HW_   4096
#define ROWS  128
#define KC    128
#define NT    256
#define NCHUNK (K_ / KC)

typedef unsigned long long ull;

__global__ __launch_bounds__(256)
void vq_zero(int* __restrict__ hist, float* __restrict__ ssq) {
    int t = blockIdx.x * blockDim.x + threadIdx.x;
    if (t < K_) hist[t] = 0;
    if (t == 0) *ssq = 0.0f;
}

__global__ __launch_bounds__(NT)
void vq_main(const float* __restrict__ x, const float* __restrict__ emb,
             float* __restrict__ zq_out, int* __restrict__ hist,
             float* __restrict__ ssq) {
    extern __shared__ __align__(16) float smem[];
    float* zt  = smem;                 // [64][128] z tile, [d][r]
    float* et  = zt + D_ * ROWS;       // [64][128] emb chunk, [d][kk]
    float* r2s = et + D_ * KC;         // [128]
    float* e2s = r2s + ROWS;           // [128]
    // overlays (used only after their hosts are dead):
    ull*   red   = (ull*)et;           // [128][16] stride 17 (17408 B <= 32768)
    int*   bidxs = (int*)r2s;          // [128]
    float* wsum  = e2s;                // [4]

    const int tid = threadIdx.x;
    const int bid = blockIdx.x;
    const int n0  = bid * ROWS;
    const int b   = n0 >> 12;
    const int hw0 = n0 & (HW_ - 1);
    const float* xb = x + (size_t)b * D_ * HW_ + hw0;

    // ---- load z tile (coalesced float4) ----
    #pragma unroll
    for (int i = 0; i < 8; ++i) {
        int li = i * NT + tid;          // 0..2047
        int d  = li >> 5;
        int r4 = (li & 31) << 2;
        float4 v = *(const float4*)(xb + (size_t)d * HW_ + r4);
        *(float4*)(zt + d * ROWS + r4) = v;
    }
    __syncthreads();

    // ---- r2 per row (mimics sum(zf*zf, axis=1)) ----
    if (tid < ROWS) {
        float s = 0.0f;
        for (int d = 0; d < D_; ++d) { float z = zt[d * ROWS + tid]; s = fmaf(z, z, s); }
        r2s[tid] = s;
    }

    const int rg  = tid >> 4;          // 0..15
    const int kg  = tid & 15;          // 0..15
    const int r0  = rg * 8;
    const int kk0 = kg * 8;

    float bd[8]; int bk[8];
    #pragma unroll
    for (int i = 0; i < 8; ++i) { bd[i] = 3.4e38f; bk[i] = 0; }

    for (int c = 0; c < NCHUNK; ++c) {
        const int kbase = c * KC;
        __syncthreads();   // protect et reuse (and publish r2s on c==0)

        // load emb chunk transposed: et[d][kk] = emb[kbase+kk][d]
        #pragma unroll
        for (int i = 0; i < 8; ++i) {
            int li = i * NT + tid;      // 0..2047
            int kk = li & (KC - 1);
            int d4 = (li >> 7) << 2;    // 0,4,..,60
            float4 v = *(const float4*)(emb + (size_t)(kbase + kk) * D_ + d4);
            et[(d4 + 0) * KC + kk] = v.x;
            et[(d4 + 1) * KC + kk] = v.y;
            et[(d4 + 2) * KC + kk] = v.z;
            et[(d4 + 3) * KC + kk] = v.w;
        }
        __syncthreads();

        if (tid < KC) {
            float s = 0.0f;
            for (int d = 0; d < D_; ++d) { float e = et[d * KC + tid]; s = fmaf(e, e, s); }
            e2s[tid] = s;
        }
        __syncthreads();

        // ---- 8x8 register tile dot products ----
        float acc[8][8];
        #pragma unroll
        for (int i = 0; i < 8; ++i)
            #pragma unroll
            for (int j = 0; j < 8; ++j) acc[i][j] = 0.0f;

        #pragma unroll 8
        for (int d = 0; d < D_; ++d) {
            const float4 za0 = *(const float4*)(zt + d * ROWS + r0);
            const float4 za1 = *(const float4*)(zt + d * ROWS + r0 + 4);
            const float4 eb0 = *(const float4*)(et + d * KC + kk0);
            const float4 eb1 = *(const float4*)(et + d * KC + kk0 + 4);
            const float zr[8] = {za0.x, za0.y, za0.z, za0.w, za1.x, za1.y, za1.z, za1.w};
            const float ek[8] = {eb0.x, eb0.y, eb0.z, eb0.w, eb1.x, eb1.y, eb1.z, eb1.w};
            #pragma unroll
            for (int i = 0; i < 8; ++i)
                #pragma unroll
                for (int j = 0; j < 8; ++j)
                    acc[i][j] = fmaf(zr[i], ek[j], acc[i][j]);
        }

        // ---- dist = (r2 + e2) - 2*dot, running argmin (first-index ties) ----
        #pragma unroll
        for (int i = 0; i < 8; ++i) {
            const float r2 = r2s[r0 + i];
            #pragma unroll
            for (int j = 0; j < 8; ++j) {
                float dist = (r2 + e2s[kk0 + j]) - 2.0f * acc[i][j];
                int k = kbase + kk0 + j;
                if (dist < bd[i]) { bd[i] = dist; bk[i] = k; }
            }
        }
    }

    __syncthreads();   // et/r2s/e2s now dead; overlays become live

    #pragma unroll
    for (int i = 0; i < 8; ++i) {
        unsigned int db = __float_as_uint(bd[i]);   // dist > 0 -> bit order == float order
        red[(size_t)(r0 + i) * 17 + kg] = ((ull)db << 32) | (unsigned int)(bk[i]);
    }
    __syncthreads();

    if (tid < ROWS) {
        ull best = red[(size_t)tid * 17];
        #pragma unroll
        for (int g = 1; g < 16; ++g) {
            ull v = red[(size_t)tid * 17 + g];
            if (v < best) best = v;
        }
        int k = (int)(best & 0xffffffffull);
        bidxs[tid] = k;
        atomicAdd(&hist[k], 1);
    }
    __syncthreads();

    // ---- gather code, write z + (e - z) (straight-through), accumulate SSQ ----
    float ls = 0.0f;
    float* outb = zq_out + (size_t)b * D_ * HW_ + hw0;
    for (int it = 0; it < 32; ++it) {
        int li = it * NT + tid;        // 0..8191
        int r  = li & (ROWS - 1);
        int d  = li >> 7;
        int k  = bidxs[r];
        float e = emb[(size_t)k * D_ + d];
        float z = zt[d * ROWS + r];
        float t = e - z;
        ls = fmaf(t, t, ls);
        outb[(size_t)d * HW_ + r] = z + t;
    }

    #pragma unroll
    for (int o = 32; o > 0; o >>= 1) ls += __shfl_down(ls, o, 64);
    int wave = tid >> 6;
    if ((tid & 63) == 0) wsum[wave] = ls;
    __syncthreads();
    if (tid == 0) {
        float s = wsum[0] + wsum[1] + wsum[2] + wsum[3];
        atomicAdd(ssq, s);
    }
}

__global__ __launch_bounds__(1024)
void vq_final(const int* __restrict__ hist, const float* __restrict__ ssq,
              float* __restrict__ out_loss, float* __restrict__ out_perp) {
    __shared__ float wred[16];
    int t = threadIdx.x;
    float cnt = (float)hist[t];
    float em  = cnt / (float)N_;
    float s   = em * logf(em + 1e-10f);
    #pragma unroll
    for (int o = 32; o > 0; o >>= 1) s += __shfl_down(s, o, 64);
    if ((t & 63) == 0) wred[t >> 6] = s;
    __syncthreads();
    if (t == 0) {
        float tot = 0.0f;
        for (int w = 0; w < 16; ++w) tot += wred[w];
        *out_perp = expf(-tot);
        float mse = *ssq / (float)(N_ * D_);
        *out_loss = mse + 0.25f * mse;   // mean((zq-z)^2) + BETA*mean((zq-z)^2)
    }
}

extern "C" void kernel_launch(void* const* d_in, const int* in_sizes, int n_in,
                              void* d_out, int out_size, void* d_ws, size_t ws_size,
                              hipStream_t stream) {
    const float* x   = (const float*)d_in[0];
    const float* emb = (const float*)d_in[1];
    float* out  = (float*)d_out;
    float* loss = out;
    float* zq   = out + 1;
    float* perp = out + 1 + (size_t)N_ * D_;
    int*   hist = (int*)d_ws;
    float* ssq  = (float*)((char*)d_ws + K_ * sizeof(int));

    vq_zero<<<dim3(4), dim3(256), 0, stream>>>(hist, ssq);

    size_t shmem = (size_t)(D_ * ROWS + D_ * KC + ROWS + KC) * sizeof(float);
    vq_main<<<dim3(N_ / ROWS), dim3(NT), shmem, stream>>>(x, emb, zq, hist, ssq);

    vq_final<<<dim3(1), dim3(1024), 0, stream>>>(hist, ssq, loss, perp);
}